// Round 9
// baseline (990.126 us; speedup 1.0000x reference)
//
#include <hip/hip_runtime.h>
#include <math.h>

#define E_TOTAL   1000000
#define HDIM      128
#define K1        256   // 2H
#define N1        512   // 4H
#define N2        128   // H
#define M_TILE    64
#define BLOCK     256

typedef _Float16 f16;
typedef _Float16 f16_4  __attribute__((ext_vector_type(4)));
typedef _Float16 f16_8  __attribute__((ext_vector_type(8)));
typedef float    f32_16 __attribute__((ext_vector_type(16)));

// ---------------- prep kernels ----------------
// 32x32x16 fragment packing (A/B frag: lane l holds [row=l&31][k=(l>>5)*8+v]):
// W1F[nt(16)][kc(16)][lane(64)][v(8)] = W1[k=kc*16+(l>>5)*8+v][n=nt*32+(l&31)]
// W2F[nt(4)][kcg(32)][lane(64)][v(8)] = W2[k=kcg*16+(l>>5)*8+v][n=nt*32+(l&31)]
__global__ void prep_weights(const float* __restrict__ W1, const float* __restrict__ W2,
                             f16* __restrict__ W1F, f16* __restrict__ W2F) {
    int t = blockIdx.x * blockDim.x + threadIdx.x;
    const int total1 = K1 * N1;           // 131072
    const int total2 = N1 * N2;           // 65536
    if (t < total1) {
        int v    = t & 7;
        int lane = (t >> 3) & 63;
        int kc   = (t >> 9) & 15;
        int nt   = t >> 13;
        int k = kc * 16 + (lane >> 5) * 8 + v;
        int n = nt * 32 + (lane & 31);
        W1F[t] = (f16)W1[k * N1 + n];
    } else if (t < total1 + total2) {
        int u = t - total1;
        int v    = u & 7;
        int lane = (u >> 3) & 63;
        int kcg  = (u >> 9) & 31;
        int nt   = u >> 14;
        int k = kcg * 16 + (lane >> 5) * 8 + v;
        int n = nt * 32 + (lane & 31);
        W2F[u] = (f16)W2[k * N2 + n];
    }
}

__global__ void prep_emb(const float* __restrict__ emb, f16* __restrict__ emb16) {
    int t = blockIdx.x * blockDim.x + threadIdx.x;   // 3.2M threads, 4 elems each
    float4 f = ((const float4*)emb)[t];
    f16_4 v = { (f16)f.x, (f16)f.y, (f16)f.z, (f16)f.w };
    ((f16_4*)emb16)[t] = v;
}

// ---------------- main kernel ----------------
// R16 = R14's 2-strip wave partition WITHOUT register pinning (R14's spill
// cause). Wave w owns edge-half et=w&1 and strips sg*2+{0,1} (sg=w>>1);
// ef/ef2 fragments are read from LDS per use -- each ds_read_b128 now feeds
// TWO MFMAs (R10 fed one). LDS b128 reads/thread: 196 -> 100; LDS pipe
// ~13.3K -> ~7.5K cyc/block (was 68% of the block interval, the largest
// pipe). Cost: W1F/W2F issued 2x per wave (wave pairs share via L1
// broadcast; L2-resident). Schedule/barriers/layouts byte-identical to R10;
// phase-0 keeps the R12-verified psi XOR swizzle (conflict-free scatter).
//   sAF [row(32)][col(64)][v(8)]    = 32 KB (gather, swizzled; sH2F overlay)
//   sBF [et(2)][kl(8)][lane(64)][8] = 16 KB (H1 quarter, single buffer)
// LDS 48 KB -> 3 blocks/CU; VGPR ~100 (acc 64 + temps) -> lb(256,3).
template <bool F16EMB>
__global__ __launch_bounds__(BLOCK, 3) void edge_mlp_kernel(
    const float* __restrict__ emb,
    const f16*   __restrict__ emb16,
    const int*   __restrict__ eidx,
    const f16*   __restrict__ W1F,
    const float* __restrict__ b1,
    const f16*   __restrict__ W2F,
    const float* __restrict__ b2,
    const float* __restrict__ W3,
    const float* __restrict__ b3,
    float* __restrict__ out)
{
    __shared__ __align__(16) f16 sAF[2 * 16 * 64 * 8];      // 32 KB
    __shared__ __align__(16) f16 sBF[2 * 8 * 64 * 8];       // 16 KB
    f16* sH2F = sAF;                                        // 16 KB overlay

    const int tid = threadIdx.x;
    const int e0  = blockIdx.x * M_TILE;

    // ---- Phase 0: gather emb[col]||emb[row] -> sAF (fragment layout, swizzled) ----
    // thread: m=tid>>2 (edge 0..63), side=(tid>>1)&1, sub=tid&1; 8x16B each.
    // physical idx16 = row*64 + (col ^ psi), psi = side*4 + sub*2 + (j&1).
    {
        const int m    = tid >> 2;
        const int side = (tid >> 1) & 1;
        const int sub  = tid & 1;
        const int met  = m >> 5;
        const int m31  = m & 31;
        const int node = eidx[side * E_TOTAL + e0 + m];
        if (F16EMB) {
            const f16* src = emb16 + (size_t)node * HDIM;
            #pragma unroll
            for (int j = 0; j < 4; ++j) {
                const int g    = side * 8 + sub * 4 + j;
                const int koff = (sub * 4 + j) * 16;       // within node row
                const int psi  = side * 4 + sub * 2 + (j & 1);
                #pragma unroll
                for (int lhp = 0; lhp < 2; ++lhp) {
                    f16_8 v = *(const f16_8*)(src + koff + lhp * 8);
                    *(f16_8*)(sAF + (((met * 16 + g) * 64 + ((lhp * 32 + m31) ^ psi)) << 3)) = v;
                }
            }
        } else {
            const float* src = emb + (size_t)node * HDIM;
            #pragma unroll
            for (int j = 0; j < 4; ++j) {
                const int g    = side * 8 + sub * 4 + j;
                const int koff = (sub * 4 + j) * 16;
                const int psi  = side * 4 + sub * 2 + (j & 1);
                #pragma unroll
                for (int lhp = 0; lhp < 2; ++lhp) {
                    float4 fa = *(const float4*)(src + koff + lhp * 8);
                    float4 fb = *(const float4*)(src + koff + lhp * 8 + 4);
                    f16_8 v = { (f16)fa.x, (f16)fa.y, (f16)fa.z, (f16)fa.w,
                                (f16)fb.x, (f16)fb.y, (f16)fb.z, (f16)fb.w };
                    *(f16_8*)(sAF + (((met * 16 + g) * 64 + ((lhp * 32 + m31) ^ psi)) << 3)) = v;
                }
            }
        }
    }
    __syncthreads();

    const int w    = tid >> 6;
    const int lane = tid & 63;
    const int l31  = lane & 31;
    const int lh   = lane >> 5;    // 0/1
    const int et   = w & 1;        // edge half this wave computes
    const int sg   = w >> 1;       // strip group: strips sg*2, sg*2+1

    f32_16 acc2[2] = {{0.f}, {0.f}};   // P2 accumulators (n2-strips sg*2, sg*2+1)

    // ---- Region 0: P1(0) only -> sBF ----
    {
        f32_16 acc1[2] = {{0.f}, {0.f}};
        #pragma unroll
        for (int kc = 0; kc < 16; ++kc) {
            const int psi = ((kc >> 3) & 1) * 4 + ((kc >> 2) & 1) * 2 + (kc & 1);
            f16_8 ef = *(const f16_8*)(sAF + (((et * 16 + kc) * 64 + (lane ^ psi)) << 3));
            #pragma unroll
            for (int sp = 0; sp < 2; ++sp) {
                const int nt = sg * 2 + sp;              // quarter 0
                f16_8 wf = *(const f16_8*)(W1F + (((nt * 16 + kc) * 64 + lane) << 3));
                acc1[sp] = __builtin_amdgcn_mfma_f32_32x32x16_f16(wf, ef, acc1[sp], 0, 0, 0);
            }
        }
        #pragma unroll
        for (int sp = 0; sp < 2; ++sp) {
            const int ls = sg * 2 + sp;
            #pragma unroll
            for (int g = 0; g < 4; ++g) {
                const float4 bv = *(const float4*)(b1 + ls * 32 + g * 8 + lh * 4);
                f16_4 hv;
                #pragma unroll
                for (int i = 0; i < 4; ++i) {
                    float v = acc1[sp][g * 4 + i] + ((const float*)&bv)[i];
                    hv[i] = (f16)(v > 0.f ? v : 0.f);
                }
                const int kl = ls * 2 + (g >> 1);
                *(f16_4*)(sBF + ((((et * 8 + kl) * 64 + (g & 1) * 32 + l31) << 3) + lh * 4)) = hv;
            }
        }
    }
    __syncthreads();

    // ---- Regions 1..3: kc{P1(q) + P2(q-1)<-sBF}; bar; H1(q)->sBF; bar ----
    #pragma unroll
    for (int q = 1; q < 4; ++q) {
        f32_16 acc1[2] = {{0.f}, {0.f}};
        #pragma unroll
        for (int kc = 0; kc < 16; ++kc) {
            const int psi = ((kc >> 3) & 1) * 4 + ((kc >> 2) & 1) * 2 + (kc & 1);
            f16_8 ef = *(const f16_8*)(sAF + (((et * 16 + kc) * 64 + (lane ^ psi)) << 3));
            #pragma unroll
            for (int sp = 0; sp < 2; ++sp) {
                const int nt = q * 4 + sg * 2 + sp;
                f16_8 wf = *(const f16_8*)(W1F + (((nt * 16 + kc) * 64 + lane) << 3));
                acc1[sp] = __builtin_amdgcn_mfma_f32_32x32x16_f16(wf, ef, acc1[sp], 0, 0, 0);
            }
            if (kc < 8) {
                const int kcg = (q - 1) * 8 + kc;        // global k-chunk for W2
                f16_8 ef2 = *(const f16_8*)(sBF + (((et * 8 + kc) * 64 + lane) << 3));
                #pragma unroll
                for (int sp2 = 0; sp2 < 2; ++sp2) {
                    f16_8 wf2 = *(const f16_8*)(W2F + ((((sg * 2 + sp2) * 32 + kcg) * 64 + lane) << 3));
                    acc2[sp2] = __builtin_amdgcn_mfma_f32_32x32x16_f16(wf2, ef2, acc2[sp2], 0, 0, 0);
                }
            }
        }
        __syncthreads();    // all P2(q-1) reads of sBF complete
        // P1(q) epilogue -> sBF (single buffer)
        #pragma unroll
        for (int sp = 0; sp < 2; ++sp) {
            const int ls = sg * 2 + sp;
            #pragma unroll
            for (int g = 0; g < 4; ++g) {
                const float4 bv = *(const float4*)(b1 + q * 128 + ls * 32 + g * 8 + lh * 4);
                f16_4 hv;
                #pragma unroll
                for (int i = 0; i < 4; ++i) {
                    float v = acc1[sp][g * 4 + i] + ((const float*)&bv)[i];
                    hv[i] = (f16)(v > 0.f ? v : 0.f);
                }
                const int kl = ls * 2 + (g >> 1);
                *(f16_4*)(sBF + ((((et * 8 + kl) * 64 + (g & 1) * 32 + l31) << 3) + lh * 4)) = hv;
            }
        }
        __syncthreads();    // H1(q) visible
    }

    // ---- Final P2(3) <- sBF ----
    {
        #pragma unroll
        for (int kc = 0; kc < 8; ++kc) {
            const int kcg = 24 + kc;
            f16_8 ef2 = *(const f16_8*)(sBF + (((et * 8 + kc) * 64 + lane) << 3));
            #pragma unroll
            for (int sp2 = 0; sp2 < 2; ++sp2) {
                f16_8 wf2 = *(const f16_8*)(W2F + ((((sg * 2 + sp2) * 32 + kcg) * 64 + lane) << 3));
                acc2[sp2] = __builtin_amdgcn_mfma_f32_32x32x16_f16(wf2, ef2, acc2[sp2], 0, 0, 0);
            }
        }
    }

    // ---- P2 epilogue -> sH2F (overlays sAF; all sAF reads done pre-q3 barrier) ----
    {
        #pragma unroll
        for (int sp2 = 0; sp2 < 2; ++sp2) {
            const int s2 = sg * 2 + sp2;
            #pragma unroll
            for (int g = 0; g < 4; ++g) {
                const float4 bv = *(const float4*)(b2 + s2 * 32 + g * 8 + lh * 4);
                f16_4 hv;
                #pragma unroll
                for (int i = 0; i < 4; ++i) {
                    float v = acc2[sp2][g * 4 + i] + ((const float*)&bv)[i];
                    hv[i] = (f16)(v > 0.f ? v : 0.f);
                }
                const int kl = s2 * 2 + (g >> 1);
                *(f16_4*)(sH2F + ((((et * 8 + kl) * 64 + (g & 1) * 32 + l31) << 3) + lh * 4)) = hv;
            }
        }
    }
    __syncthreads();

    // ---- Phase 3: logit = H2 @ W3 + b3 ; sigmoid ----
    // thread: m=tid>>2 (edge 0..63), j=tid&3 (32-k slice).
    // H2[m][kl*16+lhp*8+v] at sH2F[((met*8+kl)*64 + lhp*32 + m31)*8 + v].
    {
        const int m   = tid >> 2;
        const int j   = tid & 3;
        const int met = m >> 5;
        const int m31 = m & 31;
        float s = 0.f;
        #pragma unroll
        for (int jj = 0; jj < 2; ++jj) {
            const int kl = j * 2 + jj;
            f16_8 a = *(const f16_8*)(sH2F + (((met * 8 + kl) * 64 + m31) << 3));
            f16_8 b = *(const f16_8*)(sH2F + (((met * 8 + kl) * 64 + 32 + m31) << 3));
            const float4* w3v = (const float4*)(W3 + kl * 16);
            float4 w0 = w3v[0], w1 = w3v[1], w2 = w3v[2], w3q = w3v[3];
            s += (float)a[0]*w0.x + (float)a[1]*w0.y + (float)a[2]*w0.z + (float)a[3]*w0.w;
            s += (float)a[4]*w1.x + (float)a[5]*w1.y + (float)a[6]*w1.z + (float)a[7]*w1.w;
            s += (float)b[0]*w2.x + (float)b[1]*w2.y + (float)b[2]*w2.z + (float)b[3]*w2.w;
            s += (float)b[4]*w3q.x + (float)b[5]*w3q.y + (float)b[6]*w3q.z + (float)b[7]*w3q.w;
        }
        s += __shfl_xor(s, 1);
        s += __shfl_xor(s, 2);
        if (j == 0) {
            const float logit = s + b3[0];
            out[e0 + m] = 1.0f / (1.0f + __expf(-logit));
        }
    }
}

extern "C" void kernel_launch(void* const* d_in, const int* in_sizes, int n_in,
                              void* d_out, int out_size, void* d_ws, size_t ws_size,
                              hipStream_t stream) {
    const float* emb  = (const float*)d_in[0];
    const int*   eidx = (const int*)d_in[1];
    const float* W1   = (const float*)d_in[2];
    const float* b1   = (const float*)d_in[3];
    const float* W2   = (const float*)d_in[4];
    const float* b2   = (const float*)d_in[5];
    const float* W3   = (const float*)d_in[6];
    const float* b3   = (const float*)d_in[7];
    float* out = (float*)d_out;

    const size_t wbytes   = (size_t)(K1 * N1 + N1 * N2) * sizeof(f16);   // 384 KB
    const size_t embbytes = (size_t)100000 * HDIM * sizeof(f16);         // 25.6 MB

    f16* W1F = (f16*)d_ws;
    f16* W2F = W1F + K1 * N1;

    const int prep_total = K1 * N1 + N1 * N2;
    prep_weights<<<(prep_total + 255) / 256, 256, 0, stream>>>(W1, W2, W1F, W2F);

    if (ws_size >= wbytes + embbytes) {
        f16* emb16 = W2F + N1 * N2;
        const int cvt_threads = 100000 * HDIM / 4;   // 3.2M
        prep_emb<<<cvt_threads / 256, 256, 0, stream>>>(emb, emb16);
        edge_mlp_kernel<true><<<E_TOTAL / M_TILE, BLOCK, 0, stream>>>(
            emb, emb16, eidx, W1F, b1, W2F, b2, W3, b3, out);
    } else {
        edge_mlp_kernel<false><<<E_TOTAL / M_TILE, BLOCK, 0, stream>>>(
            emb, (const f16*)nullptr, eidx, W1F, b1, W2F, b2, W3, b3, out);
    }
}

// Round 10
// 759.468 us; speedup vs baseline: 1.3037x; 1.3037x over previous
//
#include <hip/hip_runtime.h>
#include <math.h>

#define E_TOTAL   1000000
#define N_NODES   100000
#define HDIM      128
#define K1        256   // 2H
#define N1        512   // 4H
#define N2        128   // H
#define M_TILE    64
#define BLOCK     256

typedef _Float16 f16;
typedef _Float16 f16_4  __attribute__((ext_vector_type(4)));
typedef _Float16 f16_8  __attribute__((ext_vector_type(8)));
typedef float    f32_16 __attribute__((ext_vector_type(16)));

// ---------------- prep kernels ----------------
// 32x32x16 fragment packing (A/B frag: lane l holds [row=l&31][k=(l>>5)*8+v]):
// W1F[nt(16)][kc(16)][lane(64)][v(8)] = W1[k=kc*16+(l>>5)*8+v][n=nt*32+(l&31)]
// W2F[nt(4)][kcg(32)][lane(64)][v(8)] = W2[k=kcg*16+(l>>5)*8+v][n=nt*32+(l&31)]
__global__ void prep_weights(const float* __restrict__ W1, const float* __restrict__ W2,
                             f16* __restrict__ W1F, f16* __restrict__ W2F) {
    int t = blockIdx.x * blockDim.x + threadIdx.x;
    const int total1 = K1 * N1;           // 131072
    const int total2 = N1 * N2;           // 65536
    if (t < total1) {
        int v    = t & 7;
        int lane = (t >> 3) & 63;
        int kc   = (t >> 9) & 15;
        int nt   = t >> 13;
        int k = kc * 16 + (lane >> 5) * 8 + v;
        int n = nt * 32 + (lane & 31);
        W1F[t] = (f16)W1[k * N1 + n];
    } else if (t < total1 + total2) {
        int u = t - total1;
        int v    = u & 7;
        int lane = (u >> 3) & 63;
        int kcg  = (u >> 9) & 31;
        int nt   = u >> 14;
        int k = kcg * 16 + (lane >> 5) * 8 + v;
        int n = nt * 32 + (lane & 31);
        W2F[u] = (f16)W2[k * N2 + n];
    }
}

__global__ void prep_emb(const float* __restrict__ emb, f16* __restrict__ emb16) {
    int t = blockIdx.x * blockDim.x + threadIdx.x;
    float4 f = ((const float4*)emb)[t];
    f16_4 v = { (f16)f.x, (f16)f.y, (f16)f.z, (f16)f.w };
    ((f16_4*)emb16)[t] = v;
}

// ---------------- R17: per-node precompute ----------------
// A[node][512] = emb[node]@W1[k=0..127] + b1   (b1 folded into A)
// B[node][512] = emb[node]@W1[k=128..255]
// Block: 64 sequential nodes x all 512 j; 4 waves, wave w owns j-strip q*4+w.
// Node fragments staged in LDS (coalesced f32 loads, cvt f16, psi-swizzled);
// output transposed through padded LDS for coalesced 64B-per-thread stores.
__global__ __launch_bounds__(BLOCK, 2) void precompute_AB(
    const float* __restrict__ emb, const f16* __restrict__ W1F,
    const float* __restrict__ b1,
    f16* __restrict__ Atab, f16* __restrict__ Btab)
{
    __shared__ __align__(16) f16 sNF[2 * 8 * 64 * 8];   // 16 KB node frags
    __shared__ __align__(16) f16 sOut[2 * 64 * 132];    // ~33.8 KB (pad 132)

    const int tid = threadIdx.x;
    const int n0  = blockIdx.x * 64;

    // stage node fragments: thread (nn=tid>>2, c=tid&3) loads emb[n0+nn][c*32..+32)
    {
        const int nn = tid >> 2;
        const int c  = tid & 3;
        int gn = n0 + nn; if (gn >= N_NODES) gn = N_NODES - 1;
        const float* src = emb + (size_t)gn * HDIM + c * 32;
        const int et  = nn >> 5;
        const int m31 = nn & 31;
        #pragma unroll
        for (int u = 0; u < 4; ++u) {
            float4 fa = *(const float4*)(src + u * 8);
            float4 fb = *(const float4*)(src + u * 8 + 4);
            f16_8 v = { (f16)fa.x, (f16)fa.y, (f16)fa.z, (f16)fa.w,
                        (f16)fb.x, (f16)fb.y, (f16)fb.z, (f16)fb.w };
            const int kc  = c * 2 + (u >> 1);   // 0..7
            const int lh2 = u & 1;
            *(f16_8*)(sNF + (((et * 8 + kc) * 64 + ((lh2 * 32 + m31) ^ kc)) << 3)) = v;
        }
    }
    __syncthreads();

    const int w    = tid >> 6;
    const int lane = tid & 63;
    const int l31  = lane & 31;
    const int lh   = lane >> 5;

    #pragma unroll
    for (int q = 0; q < 4; ++q) {
        #pragma unroll
        for (int T = 0; T < 2; ++T) {
            f32_16 acc[2] = {{0.f}, {0.f}};
            #pragma unroll
            for (int kc = 0; kc < 8; ++kc) {
                f16_8 wf = *(const f16_8*)(W1F +
                    ((((q * 4 + w) * 16 + T * 8 + kc) * 64 + lane) << 3));
                #pragma unroll
                for (int et = 0; et < 2; ++et) {
                    f16_8 nf = *(const f16_8*)(sNF +
                        (((et * 8 + kc) * 64 + (lane ^ kc)) << 3));
                    acc[et] = __builtin_amdgcn_mfma_f32_32x32x16_f16(wf, nf, acc[et], 0, 0, 0);
                }
            }
            // acc -> sOut[T][node][j_in_quarter], j_in_q = w*32 + g*8 + lh*4 + i
            #pragma unroll
            for (int et = 0; et < 2; ++et) {
                #pragma unroll
                for (int g = 0; g < 4; ++g) {
                    f16_4 hv;
                    #pragma unroll
                    for (int i = 0; i < 4; ++i) {
                        float v = acc[et][g * 4 + i];
                        if (T == 0) v += b1[q * 128 + w * 32 + g * 8 + lh * 4 + i];
                        hv[i] = (f16)v;
                    }
                    *(f16_4*)(&sOut[(T * 64 + et * 32 + l31) * 132 + w * 32 + g * 8 + lh * 4]) = hv;
                }
            }
        }
        __syncthreads();
        // coalesced copy-out: thread (nn, c) writes 32 f16 (64B) per table
        {
            const int nn = tid >> 2;
            const int c  = tid & 3;
            const int gn = n0 + nn;
            if (gn < N_NODES) {
                #pragma unroll
                for (int T = 0; T < 2; ++T) {
                    f16* dst = (T ? Btab : Atab) + (size_t)gn * 512 + q * 128 + c * 32;
                    #pragma unroll
                    for (int u = 0; u < 4; ++u)
                        *(f16_8*)(dst + u * 8) =
                            *(const f16_8*)(&sOut[(T * 64 + nn) * 132 + c * 32 + u * 8]);
                }
            }
        }
        __syncthreads();
    }
}

// ---------------- R17 edge kernel ----------------
// Per block: 64 edges. Phase G(h): gather relu(A[col]+B[row]) for k-half h
// into sHF (R12-verified psi-swizzled fragment layout). P2(h): 16 kcg x
// {1 wf2 + 2 ef2 + 2 MFMA} per wave (wave = n2-strip, disjoint weights).
// Epilogue + phase3 verbatim from the proven R10 kernel.
//   sHF[et(2)][kc(16)][col(64)][v(8)] = 32 KB; sH2F overlays.
// LDS 32 KB -> 4 blocks/CU; VGPR ~80 -> launch_bounds(256,4).
__global__ __launch_bounds__(BLOCK, 4) void edge_mlp2(
    const f16* __restrict__ Atab, const f16* __restrict__ Btab,
    const int* __restrict__ eidx,
    const f16* __restrict__ W2F, const float* __restrict__ b2,
    const float* __restrict__ W3, const float* __restrict__ b3,
    float* __restrict__ out)
{
    __shared__ __align__(16) f16 sHF[2 * 16 * 64 * 8];   // 32 KB
    f16* sH2F = sHF;                                     // 16 KB overlay

    const int tid = threadIdx.x;
    const int e0  = blockIdx.x * M_TILE;

    // gather roles (proven phase0 mapping)
    const int m    = tid >> 2;
    const int side = (tid >> 1) & 1;
    const int sub  = tid & 1;
    const int met  = m >> 5;
    const int m31  = m & 31;
    const int col  = eidx[e0 + m];
    const int row  = eidx[E_TOTAL + e0 + m];
    const f16* arow = Atab + (size_t)col * 512;
    const f16* brow = Btab + (size_t)row * 512;

    const int w    = tid >> 6;     // wave = n2-strip
    const int lane = tid & 63;
    const int l31  = lane & 31;
    const int lh   = lane >> 5;

    f32_16 acc2[2] = {{0.f}, {0.f}};

    #pragma unroll
    for (int h = 0; h < 2; ++h) {
        // ---- Phase G(h): relu(A[col]+B[row]) -> sHF fragments (swizzled) ----
        #pragma unroll
        for (int j = 0; j < 4; ++j) {
            const int g   = side * 8 + sub * 4 + j;     // kcg_local 0..15
            const int nof = h * 256 + g * 16;           // n-offset within row
            const int psi = side * 4 + sub * 2 + (j & 1);
            #pragma unroll
            for (int lh2 = 0; lh2 < 2; ++lh2) {
                f16_8 av = *(const f16_8*)(arow + nof + lh2 * 8);
                f16_8 bv = *(const f16_8*)(brow + nof + lh2 * 8);
                f16_8 hv;
                #pragma unroll
                for (int i = 0; i < 8; ++i) {
                    float v = (float)av[i] + (float)bv[i];
                    hv[i] = (f16)(v > 0.f ? v : 0.f);
                }
                *(f16_8*)(sHF + (((met * 16 + g) * 64 + ((lh2 * 32 + m31) ^ psi)) << 3)) = hv;
            }
        }
        __syncthreads();

        // ---- P2(h): wave w owns n2-strip w (disjoint W2) ----
        #pragma unroll
        for (int kc = 0; kc < 16; ++kc) {
            const int kcg = h * 16 + kc;
            const int psi = ((kc >> 3) & 1) * 4 + ((kc >> 2) & 1) * 2 + (kc & 1);
            f16_8 wf2 = *(const f16_8*)(W2F + (((w * 32 + kcg) * 64 + lane) << 3));
            #pragma unroll
            for (int et = 0; et < 2; ++et) {
                f16_8 ef2 = *(const f16_8*)(sHF + (((et * 16 + kc) * 64 + (lane ^ psi)) << 3));
                acc2[et] = __builtin_amdgcn_mfma_f32_32x32x16_f16(wf2, ef2, acc2[et], 0, 0, 0);
            }
        }
        __syncthreads();   // sHF reads done before next G overwrites / epilogue overlay
    }

    // ---- P2 epilogue -> sH2F (proven code, wnt->w) ----
    {
        #pragma unroll
        for (int et = 0; et < 2; ++et) {
            #pragma unroll
            for (int g = 0; g < 4; ++g) {
                const int wn = w * 32 + lh * 4 + g * 8;
                const float4 bv = *(const float4*)(b2 + wn);
                f16_4 hv;
                #pragma unroll
                for (int i = 0; i < 4; ++i) {
                    float v = acc2[et][g * 4 + i] + ((const float*)&bv)[i];
                    hv[i] = (f16)(v > 0.f ? v : 0.f);
                }
                const int kl = w * 2 + (g >> 1);
                *(f16_4*)(sH2F + ((((et * 8 + kl) * 64 + (g & 1) * 32 + l31) << 3) + lh * 4)) = hv;
            }
        }
    }
    __syncthreads();

    // ---- Phase 3 (proven code verbatim) ----
    {
        const int mm  = tid >> 2;
        const int j   = tid & 3;
        const int mt  = mm >> 5;
        const int mm31 = mm & 31;
        float s = 0.f;
        #pragma unroll
        for (int jj = 0; jj < 2; ++jj) {
            const int kl = j * 2 + jj;
            f16_8 a = *(const f16_8*)(sH2F + (((mt * 8 + kl) * 64 + mm31) << 3));
            f16_8 b = *(const f16_8*)(sH2F + (((mt * 8 + kl) * 64 + 32 + mm31) << 3));
            const float4* w3v = (const float4*)(W3 + kl * 16);
            float4 w0 = w3v[0], w1 = w3v[1], w2 = w3v[2], w3q = w3v[3];
            s += (float)a[0]*w0.x + (float)a[1]*w0.y + (float)a[2]*w0.z + (float)a[3]*w0.w;
            s += (float)a[4]*w1.x + (float)a[5]*w1.y + (float)a[6]*w1.z + (float)a[7]*w1.w;
            s += (float)b[0]*w2.x + (float)b[1]*w2.y + (float)b[2]*w2.z + (float)b[3]*w2.w;
            s += (float)b[4]*w3q.x + (float)b[5]*w3q.y + (float)b[6]*w3q.z + (float)b[7]*w3q.w;
        }
        s += __shfl_xor(s, 1);
        s += __shfl_xor(s, 2);
        if (j == 0) {
            const float logit = s + b3[0];
            out[e0 + m] = 1.0f / (1.0f + __expf(-logit));
        }
    }
}

// ---------------- fallback: proven R10 kernel (499us) ----------------
template <bool F16EMB>
__global__ __launch_bounds__(BLOCK, 3) void edge_mlp_kernel(
    const float* __restrict__ emb,
    const f16*   __restrict__ emb16,
    const int*   __restrict__ eidx,
    const f16*   __restrict__ W1F,
    const float* __restrict__ b1,
    const f16*   __restrict__ W2F,
    const float* __restrict__ b2,
    const float* __restrict__ W3,
    const float* __restrict__ b3,
    float* __restrict__ out)
{
    __shared__ __align__(16) f16 sAF[2 * 16 * 64 * 8];
    __shared__ __align__(16) f16 sBF[2 * 8 * 64 * 8];
    f16* sH2F = sAF;

    const int tid = threadIdx.x;
    const int e0  = blockIdx.x * M_TILE;
    {
        const int m    = tid >> 2;
        const int side = (tid >> 1) & 1;
        const int sub  = tid & 1;
        const int met  = m >> 5;
        const int m31  = m & 31;
        const int node = eidx[side * E_TOTAL + e0 + m];
        if (F16EMB) {
            const f16* src = emb16 + (size_t)node * HDIM;
            #pragma unroll
            for (int j = 0; j < 4; ++j) {
                const int g = side * 8 + sub * 4 + j;
                const int koff = (sub * 4 + j) * 16;
                #pragma unroll
                for (int lh = 0; lh < 2; ++lh) {
                    f16_8 v = *(const f16_8*)(src + koff + lh * 8);
                    *(f16_8*)(sAF + (((met * 16 + g) * 64 + lh * 32 + m31) << 3)) = v;
                }
            }
        } else {
            const float* src = emb + (size_t)node * HDIM;
            #pragma unroll
            for (int j = 0; j < 4; ++j) {
                const int g = side * 8 + sub * 4 + j;
                const int koff = (sub * 4 + j) * 16;
                #pragma unroll
                for (int lh = 0; lh < 2; ++lh) {
                    float4 fa = *(const float4*)(src + koff + lh * 8);
                    float4 fb = *(const float4*)(src + koff + lh * 8 + 4);
                    f16_8 v = { (f16)fa.x, (f16)fa.y, (f16)fa.z, (f16)fa.w,
                                (f16)fb.x, (f16)fb.y, (f16)fb.z, (f16)fb.w };
                    *(f16_8*)(sAF + (((met * 16 + g) * 64 + lh * 32 + m31) << 3)) = v;
                }
            }
        }
    }
    __syncthreads();

    const int wnt  = tid >> 6;
    const int lane = tid & 63;
    const int l31  = lane & 31;
    const int lh   = lane >> 5;

    f32_16 acc2[2] = {{0.f}, {0.f}};
    {
        f32_16 acc1[2] = {{0.f}, {0.f}};
        const int nt = wnt;
        #pragma unroll
        for (int kc = 0; kc < 16; ++kc) {
            f16_8 wf = *(const f16_8*)(W1F + (((nt * 16 + kc) * 64 + lane) << 3));
            #pragma unroll
            for (int et = 0; et < 2; ++et) {
                f16_8 ef = *(const f16_8*)(sAF + (((et * 16 + kc) * 64 + lane) << 3));
                acc1[et] = __builtin_amdgcn_mfma_f32_32x32x16_f16(wf, ef, acc1[et], 0, 0, 0);
            }
        }
        #pragma unroll
        for (int et = 0; et < 2; ++et) {
            #pragma unroll
            for (int g = 0; g < 4; ++g) {
                const int wnl = wnt * 32 + lh * 4 + g * 8;
                const float4 bv = *(const float4*)(b1 + wnl);
                f16_4 hv;
                #pragma unroll
                for (int i = 0; i < 4; ++i) {
                    float v = acc1[et][g * 4 + i] + ((const float*)&bv)[i];
                    hv[i] = (f16)(v > 0.f ? v : 0.f);
                }
                const int kl = wnt * 2 + (g >> 1);
                *(f16_4*)(sBF + ((((et * 8 + kl) * 64 + (g & 1) * 32 + l31) << 3) + lh * 4)) = hv;
            }
        }
    }
    __syncthreads();

    #pragma unroll
    for (int q = 1; q < 4; ++q) {
        f32_16 acc1[2] = {{0.f}, {0.f}};
        const int nt = q * 4 + wnt;
        #pragma unroll
        for (int kc = 0; kc < 16; ++kc) {
            f16_8 wf = *(const f16_8*)(W1F + (((nt * 16 + kc) * 64 + lane) << 3));
            #pragma unroll
            for (int et = 0; et < 2; ++et) {
                f16_8 ef = *(const f16_8*)(sAF + (((et * 16 + kc) * 64 + lane) << 3));
                acc1[et] = __builtin_amdgcn_mfma_f32_32x32x16_f16(wf, ef, acc1[et], 0, 0, 0);
            }
            if (kc < 8) {
                const int kcg = (q - 1) * 8 + kc;
                f16_8 wf2 = *(const f16_8*)(W2F + (((wnt * 32 + kcg) * 64 + lane) << 3));
                #pragma unroll
                for (int et = 0; et < 2; ++et) {
                    f16_8 ef2 = *(const f16_8*)(sBF + (((et * 8 + kc) * 64 + lane) << 3));
                    acc2[et] = __builtin_amdgcn_mfma_f32_32x32x16_f16(wf2, ef2, acc2[et], 0, 0, 0);
                }
            }
        }
        __syncthreads();
        #pragma unroll
        for (int et = 0; et < 2; ++et) {
            #pragma unroll
            for (int g = 0; g < 4; ++g) {
                const int wnl = wnt * 32 + lh * 4 + g * 8;
                const float4 bv = *(const float4*)(b1 + q * 128 + wnl);
                f16_4 hv;
                #pragma unroll
                for (int i = 0; i < 4; ++i) {
                    float v = acc1[et][g * 4 + i] + ((const float*)&bv)[i];
                    hv[i] = (f16)(v > 0.f ? v : 0.f);
                }
                const int kl = wnt * 2 + (g >> 1);
                *(f16_4*)(sBF + ((((et * 8 + kl) * 64 + (g & 1) * 32 + l31) << 3) + lh * 4)) = hv;
            }
        }
        __syncthreads();
    }
    {
        #pragma unroll
        for (int kc = 0; kc < 8; ++kc) {
            const int kcg = 24 + kc;
            f16_8 wf2 = *(const f16_8*)(W2F + (((wnt * 32 + kcg) * 64 + lane) << 3));
            #pragma unroll
            for (int et = 0; et < 2; ++et) {
                f16_8 ef2 = *(const f16_8*)(sBF + (((et * 8 + kc) * 64 + lane) << 3));
                acc2[et] = __builtin_amdgcn_mfma_f32_32x32x16_f16(wf2, ef2, acc2[et], 0, 0, 0);
            }
        }
    }
    {
        #pragma unroll
        for (int et = 0; et < 2; ++et) {
            #pragma unroll
            for (int g = 0; g < 4; ++g) {
                const int wn = wnt * 32 + lh * 4 + g * 8;
                const float4 bv = *(const float4*)(b2 + wn);
                f16_4 hv;
                #pragma unroll
                for (int i = 0; i < 4; ++i) {
                    float v = acc2[et][g * 4 + i] + ((const float*)&bv)[i];
                    hv[i] = (f16)(v > 0.f ? v : 0.f);
                }
                const int kl = wnt * 2 + (g >> 1);
                *(f16_4*)(sH2F + ((((et * 8 + kl) * 64 + (g & 1) * 32 + l31) << 3) + lh * 4)) = hv;
            }
        }
    }
    __syncthreads();
    {
        const int m   = tid >> 2;
        const int j   = tid & 3;
        const int met = m >> 5;
        const int m31 = m & 31;
        float s = 0.f;
        #pragma unroll
        for (int jj = 0; jj < 2; ++jj) {
            const int kl = j * 2 + jj;
            f16_8 a = *(const f16_8*)(sH2F + (((met * 8 + kl) * 64 + m31) << 3));
            f16_8 b = *(const f16_8*)(sH2F + (((met * 8 + kl) * 64 + 32 + m31) << 3));
            const float4* w3v = (const float4*)(W3 + kl * 16);
            float4 w0 = w3v[0], w1 = w3v[1], w2 = w3v[2], w3q = w3v[3];
            s += (float)a[0]*w0.x + (float)a[1]*w0.y + (float)a[2]*w0.z + (float)a[3]*w0.w;
            s += (float)a[4]*w1.x + (float)a[5]*w1.y + (float)a[6]*w1.z + (float)a[7]*w1.w;
            s += (float)b[0]*w2.x + (float)b[1]*w2.y + (float)b[2]*w2.z + (float)b[3]*w2.w;
            s += (float)b[4]*w3q.x + (float)b[5]*w3q.y + (float)b[6]*w3q.z + (float)b[7]*w3q.w;
        }
        s += __shfl_xor(s, 1);
        s += __shfl_xor(s, 2);
        if (j == 0) {
            const float logit = s + b3[0];
            out[e0 + m] = 1.0f / (1.0f + __expf(-logit));
        }
    }
}

extern "C" void kernel_launch(void* const* d_in, const int* in_sizes, int n_in,
                              void* d_out, int out_size, void* d_ws, size_t ws_size,
                              hipStream_t stream) {
    const float* emb  = (const float*)d_in[0];
    const int*   eidx = (const int*)d_in[1];
    const float* W1   = (const float*)d_in[2];
    const float* b1   = (const float*)d_in[3];
    const float* W2   = (const float*)d_in[4];
    const float* b2   = (const float*)d_in[5];
    const float* W3   = (const float*)d_in[6];
    const float* b3   = (const float*)d_in[7];
    float* out = (float*)d_out;

    const size_t wbytes   = (size_t)(K1 * N1 + N1 * N2) * sizeof(f16);     // 384 KB
    const size_t embbytes = (size_t)N_NODES * HDIM * sizeof(f16);          // 25.6 MB
    const size_t tabbytes = (size_t)N_NODES * 512 * sizeof(f16);           // 102.4 MB
    const size_t need_new = wbytes + 2 * tabbytes;                         // ~205 MB

    f16* W1F = (f16*)d_ws;
    f16* W2F = W1F + K1 * N1;

    const int prep_total = K1 * N1 + N1 * N2;
    prep_weights<<<(prep_total + 255) / 256, 256, 0, stream>>>(W1, W2, W1F, W2F);

    if (ws_size >= need_new) {
        // R17 path: precompute per-node A/B, then gather+P2 edge kernel
        f16* Atab = W2F + N1 * N2;
        f16* Btab = Atab + (size_t)N_NODES * 512;
        precompute_AB<<<(N_NODES + 63) / 64, BLOCK, 0, stream>>>(emb, W1F, b1, Atab, Btab);
        edge_mlp2<<<E_TOTAL / M_TILE, BLOCK, 0, stream>>>(
            Atab, Btab, eidx, W2F, b2, W3, b3, out);
    } else if (ws_size >= wbytes + embbytes) {
        f16* emb16 = W2F + N1 * N2;
        const int cvt_threads = N_NODES * HDIM / 4;
        prep_emb<<<cvt_threads / 256, 256, 0, stream>>>(emb, emb16);
        edge_mlp_kernel<true><<<E_TOTAL / M_TILE, BLOCK, 0, stream>>>(
            emb, emb16, eidx, W1F, b1, W2F, b2, W3, b3, out);
    } else {
        edge_mlp_kernel<false><<<E_TOTAL / M_TILE, BLOCK, 0, stream>>>(
            emb, (const f16*)nullptr, eidx, W1F, b1, W2F, b2, W3, b3, out);
    }
}

// Round 12
// 679.932 us; speedup vs baseline: 1.4562x; 1.1170x over previous
//
#include <hip/hip_runtime.h>
#include <math.h>

#define E_TOTAL   1000000
#define N_NODES   100000
#define HDIM      128
#define K1        256   // 2H
#define N1        512   // 4H
#define N2        128   // H
#define M_TILE    64
#define BLOCK     256

typedef _Float16 f16;
typedef _Float16 f16_4  __attribute__((ext_vector_type(4)));
typedef _Float16 f16_8  __attribute__((ext_vector_type(8)));
typedef float    f32_16 __attribute__((ext_vector_type(16)));

// ---------------- prep kernels ----------------
// 32x32x16 fragment packing (A/B frag: lane l holds [row=l&31][k=(l>>5)*8+v]):
// W1F[nt(16)][kc(16)][lane(64)][v(8)] = W1[k=kc*16+(l>>5)*8+v][n=nt*32+(l&31)]
// W2F[nt(4)][kcg(32)][lane(64)][v(8)] = W2[k=kcg*16+(l>>5)*8+v][n=nt*32+(l&31)]
__global__ void prep_weights(const float* __restrict__ W1, const float* __restrict__ W2,
                             f16* __restrict__ W1F, f16* __restrict__ W2F) {
    int t = blockIdx.x * blockDim.x + threadIdx.x;
    const int total1 = K1 * N1;           // 131072
    const int total2 = N1 * N2;           // 65536
    if (t < total1) {
        int v    = t & 7;
        int lane = (t >> 3) & 63;
        int kc   = (t >> 9) & 15;
        int nt   = t >> 13;
        int k = kc * 16 + (lane >> 5) * 8 + v;
        int n = nt * 32 + (lane & 31);
        W1F[t] = (f16)W1[k * N1 + n];
    } else if (t < total1 + total2) {
        int u = t - total1;
        int v    = u & 7;
        int lane = (u >> 3) & 63;
        int kcg  = (u >> 9) & 31;
        int nt   = u >> 14;
        int k = kcg * 16 + (lane >> 5) * 8 + v;
        int n = nt * 32 + (lane & 31);
        W2F[u] = (f16)W2[k * N2 + n];
    }
}

__global__ void prep_emb(const float* __restrict__ emb, f16* __restrict__ emb16) {
    int t = blockIdx.x * blockDim.x + threadIdx.x;
    float4 f = ((const float4*)emb)[t];
    f16_4 v = { (f16)f.x, (f16)f.y, (f16)f.z, (f16)f.w };
    ((f16_4*)emb16)[t] = v;
}

// ---------------- R18 precompute: A[node][512] = emb[node]@W1_top + b1 ----
// Derived from R17's HW-verified precompute_AB with the B half deleted.
// Block: 64 nodes x 512 j; 4 waves, wave w owns j-strip q*4+w per quarter.
__global__ __launch_bounds__(BLOCK, 4) void precompute_A(
    const float* __restrict__ emb, const f16* __restrict__ W1F,
    const float* __restrict__ b1, f16* __restrict__ Atab)
{
    __shared__ __align__(16) f16 sNF[2 * 8 * 64 * 8];   // 16 KB node frags
    __shared__ __align__(16) f16 sOut[64 * 132];        // 16.5 KB (pad 132)

    const int tid = threadIdx.x;
    const int n0  = blockIdx.x * 64;

    {   // stage node fragments (coalesced f32 loads, cvt f16, ^kc swizzle)
        const int nn = tid >> 2;
        const int c  = tid & 3;
        int gn = n0 + nn; if (gn >= N_NODES) gn = N_NODES - 1;
        const float* src = emb + (size_t)gn * HDIM + c * 32;
        const int et  = nn >> 5;
        const int m31 = nn & 31;
        #pragma unroll
        for (int u = 0; u < 4; ++u) {
            float4 fa = *(const float4*)(src + u * 8);
            float4 fb = *(const float4*)(src + u * 8 + 4);
            f16_8 v = { (f16)fa.x, (f16)fa.y, (f16)fa.z, (f16)fa.w,
                        (f16)fb.x, (f16)fb.y, (f16)fb.z, (f16)fb.w };
            const int kc  = c * 2 + (u >> 1);   // 0..7
            const int lh2 = u & 1;
            *(f16_8*)(sNF + (((et * 8 + kc) * 64 + ((lh2 * 32 + m31) ^ kc)) << 3)) = v;
        }
    }
    __syncthreads();

    const int w    = tid >> 6;
    const int lane = tid & 63;
    const int l31  = lane & 31;
    const int lh   = lane >> 5;

    #pragma unroll
    for (int q = 0; q < 4; ++q) {
        f32_16 acc[2] = {{0.f}, {0.f}};
        #pragma unroll
        for (int kc = 0; kc < 8; ++kc) {    // k 0..127 = W1 top half
            f16_8 wf = *(const f16_8*)(W1F +
                ((((q * 4 + w) * 16 + kc) * 64 + lane) << 3));
            #pragma unroll
            for (int et = 0; et < 2; ++et) {
                f16_8 nf = *(const f16_8*)(sNF +
                    (((et * 8 + kc) * 64 + (lane ^ kc)) << 3));
                acc[et] = __builtin_amdgcn_mfma_f32_32x32x16_f16(wf, nf, acc[et], 0, 0, 0);
            }
        }
        #pragma unroll
        for (int et = 0; et < 2; ++et) {
            #pragma unroll
            for (int g = 0; g < 4; ++g) {
                f16_4 hv;
                #pragma unroll
                for (int i = 0; i < 4; ++i) {
                    float v = acc[et][g * 4 + i]
                            + b1[q * 128 + w * 32 + g * 8 + lh * 4 + i];
                    hv[i] = (f16)v;
                }
                *(f16_4*)(&sOut[(et * 32 + l31) * 132 + w * 32 + g * 8 + lh * 4]) = hv;
            }
        }
        __syncthreads();
        {   // coalesced copy-out: thread (nn,c) writes 64B
            const int nn = tid >> 2;
            const int c  = tid & 3;
            const int gn = n0 + nn;
            if (gn < N_NODES) {
                f16* dst = Atab + (size_t)gn * 512 + q * 128 + c * 32;
                #pragma unroll
                for (int u = 0; u < 4; ++u)
                    *(f16_8*)(dst + u * 8) =
                        *(const f16_8*)(&sOut[nn * 132 + c * 32 + u * 8]);
            }
        }
        __syncthreads();
    }
}

// ---------------- R18 edge kernel ----------------
// = proven R10 schedule with: phase0 gathering ONLY emb16[row] (16 KB sAF,
// psi-swizzled per R12/R15), P1 kc-loop halved (bottom-half W1F, k=128..255),
// interleaved 1:1 with P2, and the P1-epilogue bias replaced by the Atab
// gather (b1 folded into A at precompute). Gathered set = Atab 102 MB +
// emb16 25.6 MB -> L3-resident.
//   sAF [et(2)][kc(8)][col(64)][v(8)] = 16 KB (swizzled; sH2F overlay)
//   sBF [et(2)][kl(8)][lane(64)][8]   = 16 KB (H1 quarter, single buffer)
// LDS 32 KB -> 4 blocks/CU; VGPR ~105 -> launch_bounds(256,4).
__global__ __launch_bounds__(BLOCK, 4) void edge_mlp3(
    const f16* __restrict__ emb16,
    const f16* __restrict__ Atab,
    const int* __restrict__ eidx,
    const f16* __restrict__ W1F,
    const f16* __restrict__ W2F,
    const float* __restrict__ b2,
    const float* __restrict__ W3,
    const float* __restrict__ b3,
    float* __restrict__ out)
{
    __shared__ __align__(16) f16 sAF[2 * 8 * 64 * 8];   // 16 KB
    __shared__ __align__(16) f16 sBF[2 * 8 * 64 * 8];   // 16 KB
    f16* sH2F = sAF;                                    // 16 KB overlay

    const int tid = threadIdx.x;
    const int e0  = blockIdx.x * M_TILE;

    // ---- Phase 0: gather emb16[row] -> sAF (fragment layout, swizzled) ----
    // thread: m=tid>>2 (edge 0..63), sub=tid&3; g = sub*2+jj (0..7); 4x16B.
    {
        const int m    = tid >> 2;
        const int sub  = tid & 3;
        const int met  = m >> 5;
        const int m31  = m & 31;
        const int node = eidx[E_TOTAL + e0 + m];        // row side
        const f16* src = emb16 + (size_t)node * HDIM;
        #pragma unroll
        for (int jj = 0; jj < 2; ++jj) {
            const int g   = sub * 2 + jj;
            const int psi = ((g >> 2) & 1) * 2 + (g & 1);
            #pragma unroll
            for (int lhp = 0; lhp < 2; ++lhp) {
                f16_8 v = *(const f16_8*)(src + g * 16 + lhp * 8);
                *(f16_8*)(sAF + (((met * 8 + g) * 64 + ((lhp * 32 + m31) ^ psi)) << 3)) = v;
            }
        }
    }
    __syncthreads();

    const int wnt  = tid >> 6;     // wave 0..3 = n-strip in quarter / P2 n-strip
    const int lane = tid & 63;
    const int l31  = lane & 31;
    const int lh   = lane >> 5;    // 0/1

    // col-side node ids for the Atab epilogue gather (edge l31 and 32+l31)
    int cols[2];
    cols[0] = eidx[e0 + l31];
    cols[1] = eidx[e0 + 32 + l31];

    f32_16 acc2[2] = {{0.f}, {0.f}};   // P2 accumulators (both edge tiles)

    // ---- Region 0: P1(0) only -> sBF ----
    {
        f32_16 acc1[2] = {{0.f}, {0.f}};
        #pragma unroll
        for (int kc = 0; kc < 8; ++kc) {
            f16_8 wf = *(const f16_8*)(W1F + (((wnt * 16 + 8 + kc) * 64 + lane) << 3));
            const int psi = ((kc >> 2) & 1) * 2 + (kc & 1);
            #pragma unroll
            for (int et = 0; et < 2; ++et) {
                f16_8 ef = *(const f16_8*)(sAF + (((et * 8 + kc) * 64 + (lane ^ psi)) << 3));
                acc1[et] = __builtin_amdgcn_mfma_f32_32x32x16_f16(wf, ef, acc1[et], 0, 0, 0);
            }
        }
        #pragma unroll
        for (int et = 0; et < 2; ++et) {
            #pragma unroll
            for (int g = 0; g < 4; ++g) {
                const int wnl = wnt * 32 + lh * 4 + g * 8;
                const f16_4 av = *(const f16_4*)(Atab + (size_t)cols[et] * 512 + wnl);
                f16_4 hv;
                #pragma unroll
                for (int i = 0; i < 4; ++i) {
                    float v = acc1[et][g * 4 + i] + (float)av[i];
                    hv[i] = (f16)(v > 0.f ? v : 0.f);
                }
                const int kl = wnt * 2 + (g >> 1);
                *(f16_4*)(sBF + ((((et * 8 + kl) * 64 + (g & 1) * 32 + l31) << 3) + lh * 4)) = hv;
            }
        }
    }
    __syncthreads();

    // ---- Regions 1..3: kc{P1(q) + P2(q-1)<-sBF, 1:1}; bar; H1(q)->sBF; bar ----
    #pragma unroll
    for (int q = 1; q < 4; ++q) {
        f32_16 acc1[2] = {{0.f}, {0.f}};
        const int nt = q * 4 + wnt;
        #pragma unroll
        for (int kc = 0; kc < 8; ++kc) {
            f16_8 wf = *(const f16_8*)(W1F + (((nt * 16 + 8 + kc) * 64 + lane) << 3));
            const int psi = ((kc >> 2) & 1) * 2 + (kc & 1);
            #pragma unroll
            for (int et = 0; et < 2; ++et) {
                f16_8 ef = *(const f16_8*)(sAF + (((et * 8 + kc) * 64 + (lane ^ psi)) << 3));
                acc1[et] = __builtin_amdgcn_mfma_f32_32x32x16_f16(wf, ef, acc1[et], 0, 0, 0);
            }
            {
                const int kcg = (q - 1) * 8 + kc;        // global k-chunk for W2
                f16_8 wf2 = *(const f16_8*)(W2F + (((wnt * 32 + kcg) * 64 + lane) << 3));
                #pragma unroll
                for (int et = 0; et < 2; ++et) {
                    f16_8 ef2 = *(const f16_8*)(sBF + (((et * 8 + kc) * 64 + lane) << 3));
                    acc2[et] = __builtin_amdgcn_mfma_f32_32x32x16_f16(wf2, ef2, acc2[et], 0, 0, 0);
                }
            }
        }
        __syncthreads();    // all P2(q-1) reads of sBF complete
        // P1(q) epilogue -> sBF (A[col] add + relu)
        #pragma unroll
        for (int et = 0; et < 2; ++et) {
            #pragma unroll
            for (int g = 0; g < 4; ++g) {
                const int wnl = wnt * 32 + lh * 4 + g * 8;
                const f16_4 av = *(const f16_4*)(Atab + (size_t)cols[et] * 512 + q * 128 + wnl);
                f16_4 hv;
                #pragma unroll
                for (int i = 0; i < 4; ++i) {
                    float v = acc1[et][g * 4 + i] + (float)av[i];
                    hv[i] = (f16)(v > 0.f ? v : 0.f);
                }
                const int kl = wnt * 2 + (g >> 1);
                *(f16_4*)(sBF + ((((et * 8 + kl) * 64 + (g & 1) * 32 + l31) << 3) + lh * 4)) = hv;
            }
        }
        __syncthreads();    // H1(q) visible
    }

    // ---- Final P2(3) <- sBF ----
    {
        #pragma unroll
        for (int kc = 0; kc < 8; ++kc) {
            const int kcg = 24 + kc;
            f16_8 wf2 = *(const f16_8*)(W2F + (((wnt * 32 + kcg) * 64 + lane) << 3));
            #pragma unroll
            for (int et = 0; et < 2; ++et) {
                f16_8 ef2 = *(const f16_8*)(sBF + (((et * 8 + kc) * 64 + lane) << 3));
                acc2[et] = __builtin_amdgcn_mfma_f32_32x32x16_f16(wf2, ef2, acc2[et], 0, 0, 0);
            }
        }
    }

    // ---- P2 epilogue -> sH2F (overlays sAF; all sAF reads done pre-q3 barrier) ----
    {
        #pragma unroll
        for (int et = 0; et < 2; ++et) {
            #pragma unroll
            for (int g = 0; g < 4; ++g) {
                const int wn = wnt * 32 + lh * 4 + g * 8;
                const float4 bv = *(const float4*)(b2 + wn);
                f16_4 hv;
                #pragma unroll
                for (int i = 0; i < 4; ++i) {
                    float v = acc2[et][g * 4 + i] + ((const float*)&bv)[i];
                    hv[i] = (f16)(v > 0.f ? v : 0.f);
                }
                const int kl = wnt * 2 + (g >> 1);
                *(f16_4*)(sH2F + ((((et * 8 + kl) * 64 + (g & 1) * 32 + l31) << 3) + lh * 4)) = hv;
            }
        }
    }
    __syncthreads();

    // ---- Phase 3: logit = H2 @ W3 + b3 ; sigmoid (proven code) ----
    {
        const int m   = tid >> 2;
        const int j   = tid & 3;
        const int met = m >> 5;
        const int m31 = m & 31;
        float s = 0.f;
        #pragma unroll
        for (int jj = 0; jj < 2; ++jj) {
            const int kl = j * 2 + jj;
            f16_8 a = *(const f16_8*)(sH2F + (((met * 8 + kl) * 64 + m31) << 3));
            f16_8 b = *(const f16_8*)(sH2F + (((met * 8 + kl) * 64 + 32 + m31) << 3));
            const float4* w3v = (const float4*)(W3 + kl * 16);
            float4 w0 = w3v[0], w1 = w3v[1], w2 = w3v[2], w3q = w3v[3];
            s += (float)a[0]*w0.x + (float)a[1]*w0.y + (float)a[2]*w0.z + (float)a[3]*w0.w;
            s += (float)a[4]*w1.x + (float)a[5]*w1.y + (float)a[6]*w1.z + (float)a[7]*w1.w;
            s += (float)b[0]*w2.x + (float)b[1]*w2.y + (float)b[2]*w2.z + (float)b[3]*w2.w;
            s += (float)b[4]*w3q.x + (float)b[5]*w3q.y + (float)b[6]*w3q.z + (float)b[7]*w3q.w;
        }
        s += __shfl_xor(s, 1);
        s += __shfl_xor(s, 2);
        if (j == 0) {
            const float logit = s + b3[0];
            out[e0 + m] = 1.0f / (1.0f + __expf(-logit));
        }
    }
}

// ---------------- fallback: proven R10 kernel (499us) ----------------
template <bool F16EMB>
__global__ __launch_bounds__(BLOCK, 3) void edge_mlp_kernel(
    const float* __restrict__ emb,
    const f16*   __restrict__ emb16,
    const int*   __restrict__ eidx,
    const f16*   __restrict__ W1F,
    const float* __restrict__ b1,
    const f16*   __restrict__ W2F,
    const float* __restrict__ b2,
    const float* __restrict__ W3,
    const float* __restrict__ b3,
    float* __restrict__ out)
{
    __shared__ __align__(16) f16 sAF[2 * 16 * 64 * 8];
    __shared__ __align__(16) f16 sBF[2 * 8 * 64 * 8];
    f16* sH2F = sAF;

    const int tid = threadIdx.x;
    const int e0  = blockIdx.x * M_TILE;
    {
        const int m    = tid >> 2;
        const int side = (tid >> 1) & 1;
        const int sub  = tid & 1;
        const int met  = m >> 5;
        const int m31  = m & 31;
        const int node = eidx[side * E_TOTAL + e0 + m];
        if (F16EMB) {
            const f16* src = emb16 + (size_t)node * HDIM;
            #pragma unroll
            for (int j = 0; j < 4; ++j) {
                const int g = side * 8 + sub * 4 + j;
                const int koff = (sub * 4 + j) * 16;
                #pragma unroll
                for (int lh = 0; lh < 2; ++lh) {
                    f16_8 v = *(const f16_8*)(src + koff + lh * 8);
                    *(f16_8*)(sAF + (((met * 16 + g) * 64 + lh * 32 + m31) << 3)) = v;
                }
            }
        } else {
            const float* src = emb + (size_t)node * HDIM;
            #pragma unroll
            for (int j = 0; j < 4; ++j) {
                const int g = side * 8 + sub * 4 + j;
                const int koff = (sub * 4 + j) * 16;
                #pragma unroll
                for (int lh = 0; lh < 2; ++lh) {
                    float4 fa = *(const float4*)(src + koff + lh * 8);
                    float4 fb = *(const float4*)(src + koff + lh * 8 + 4);
                    f16_8 v = { (f16)fa.x, (f16)fa.y, (f16)fa.z, (f16)fa.w,
                                (f16)fb.x, (f16)fb.y, (f16)fb.z, (f16)fb.w };
                    *(f16_8*)(sAF + (((met * 16 + g) * 64 + lh * 32 + m31) << 3)) = v;
                }
            }
        }
    }
    __syncthreads();

    const int wnt  = tid >> 6;
    const int lane = tid & 63;
    const int l31  = lane & 31;
    const int lh   = lane >> 5;

    f32_16 acc2[2] = {{0.f}, {0.f}};
    {
        f32_16 acc1[2] = {{0.f}, {0.f}};
        const int nt = wnt;
        #pragma unroll
        for (int kc = 0; kc < 16; ++kc) {
            f16_8 wf = *(const f16_8*)(W1F + (((nt * 16 + kc) * 64 + lane) << 3));
            #pragma unroll
            for (int et = 0; et < 2; ++et) {
                f16_8 ef = *(const f16_8*)(sAF + (((et * 16 + kc) * 64 + lane) << 3));
                acc1[et] = __builtin_amdgcn_mfma_f32_32x32x16_f16(wf, ef, acc1[et], 0, 0, 0);
            }
        }
        #pragma unroll
        for (int et = 0; et < 2; ++et) {
            #pragma unroll
            for (int g = 0; g < 4; ++g) {
                const int wnl = wnt * 32 + lh * 4 + g * 8;
                const float4 bv = *(const float4*)(b1 + wnl);
                f16_4 hv;
                #pragma unroll
                for (int i = 0; i < 4; ++i) {
                    float v = acc1[et][g * 4 + i] + ((const float*)&bv)[i];
                    hv[i] = (f16)(v > 0.f ? v : 0.f);
                }
                const int kl = wnt * 2 + (g >> 1);
                *(f16_4*)(sBF + ((((et * 8 + kl) * 64 + (g & 1) * 32 + l31) << 3) + lh * 4)) = hv;
            }
        }
    }
    __syncthreads();

    #pragma unroll
    for (int q = 1; q < 4; ++q) {
        f32_16 acc1[2] = {{0.f}, {0.f}};
        const int nt = q * 4 + wnt;
        #pragma unroll
        for (int kc = 0; kc < 16; ++kc) {
            f16_8 wf = *(const f16_8*)(W1F + (((nt * 16 + kc) * 64 + lane) << 3));
            #pragma unroll
            for (int et = 0; et < 2; ++et) {
                f16_8 ef = *(const f16_8*)(sAF + (((et * 16 + kc) * 64 + lane) << 3));
                acc1[et] = __builtin_amdgcn_mfma_f32_32x32x16_f16(wf, ef, acc1[et], 0, 0, 0);
            }
            if (kc < 8) {
                const int kcg = (q - 1) * 8 + kc;
                f16_8 wf2 = *(const f16_8*)(W2F + (((wnt * 32 + kcg) * 64 + lane) << 3));
                #pragma unroll
                for (int et = 0; et < 2; ++et) {
                    f16_8 ef2 = *(const f16_8*)(sBF + (((et * 8 + kc) * 64 + lane) << 3));
                    acc2[et] = __builtin_amdgcn_mfma_f32_32x32x16_f16(wf2, ef2, acc2[et], 0, 0, 0);
                }
            }
        }
        __syncthreads();
        #pragma unroll
        for (int et = 0; et < 2; ++et) {
            #pragma unroll
            for (int g = 0; g < 4; ++g) {
                const int wnl = wnt * 32 + lh * 4 + g * 8;
                const float4 bv = *(const float4*)(b1 + q * 128 + wnl);
                f16_4 hv;
                #pragma unroll
                for (int i = 0; i < 4; ++i) {
                    float v = acc1[et][g * 4 + i] + ((const float*)&bv)[i];
                    hv[i] = (f16)(v > 0.f ? v : 0.f);
                }
                const int kl = wnt * 2 + (g >> 1);
                *(f16_4*)(sBF + ((((et * 8 + kl) * 64 + (g & 1) * 32 + l31) << 3) + lh * 4)) = hv;
            }
        }
        __syncthreads();
    }
    {
        #pragma unroll
        for (int kc = 0; kc < 8; ++kc) {
            const int kcg = 24 + kc;
            f16_8 wf2 = *(const f16_8*)(W2F + (((wnt * 32 + kcg) * 64 + lane) << 3));
            #pragma unroll
            for (int et = 0; et < 2; ++et) {
                f16_8 ef2 = *(const f16_8*)(sBF + (((et * 8 + kc) * 64 + lane) << 3));
                acc2[et] = __builtin_amdgcn_mfma_f32_32x32x16_f16(wf2, ef2, acc2[et], 0, 0, 0);
            }
        }
    }
    {
        #pragma unroll
        for (int et = 0; et < 2; ++et) {
            #pragma unroll
            for (int g = 0; g < 4; ++g) {
                const int wn = wnt * 32 + lh * 4 + g * 8;
                const float4 bv = *(const float4*)(b2 + wn);
                f16_4 hv;
                #pragma unroll
                for (int i = 0; i < 4; ++i) {
                    float v = acc2[et][g * 4 + i] + ((const float*)&bv)[i];
                    hv[i] = (f16)(v > 0.f ? v : 0.f);
                }
                const int kl = wnt * 2 + (g >> 1);
                *(f16_4*)(sH2F + ((((et * 8 + kl) * 64 + (g & 1) * 32 + l31) << 3) + lh * 4)) = hv;
            }
        }
    }
    __syncthreads();
    {
        const int m   = tid >> 2;
        const int j   = tid & 3;
        const int met = m >> 5;
        const int m31 = m & 31;
        float s = 0.f;
        #pragma unroll
        for (int jj = 0; jj < 2; ++jj) {
            const int kl = j * 2 + jj;
            f16_8 a = *(const f16_8*)(sH2F + (((met * 8 + kl) * 64 + m31) << 3));
            f16_8 b = *(const f16_8*)(sH2F + (((met * 8 + kl) * 64 + 32 + m31) << 3));
            const float4* w3v = (const float4*)(W3 + kl * 16);
            float4 w0 = w3v[0], w1 = w3v[1], w2 = w3v[2], w3q = w3v[3];
            s += (float)a[0]*w0.x + (float)a[1]*w0.y + (float)a[2]*w0.z + (float)a[3]*w0.w;
            s += (float)a[4]*w1.x + (float)a[5]*w1.y + (float)a[6]*w1.z + (float)a[7]*w1.w;
            s += (float)b[0]*w2.x + (float)b[1]*w2.y + (float)b[2]*w2.z + (float)b[3]*w2.w;
            s += (float)b[4]*w3q.x + (float)b[5]*w3q.y + (float)b[6]*w3q.z + (float)b[7]*w3q.w;
        }
        s += __shfl_xor(s, 1);
        s += __shfl_xor(s, 2);
        if (j == 0) {
            const float logit = s + b3[0];
            out[e0 + m] = 1.0f / (1.0f + __expf(-logit));
        }
    }
}

extern "C" void kernel_launch(void* const* d_in, const int* in_sizes, int n_in,
                              void* d_out, int out_size, void* d_ws, size_t ws_size,
                              hipStream_t stream) {
    const float* emb  = (const float*)d_in[0];
    const int*   eidx = (const int*)d_in[1];
    const float* W1   = (const float*)d_in[2];
    const float* b1   = (const float*)d_in[3];
    const float* W2   = (const float*)d_in[4];
    const float* b2   = (const float*)d_in[5];
    const float* W3   = (const float*)d_in[6];
    const float* b3   = (const float*)d_in[7];
    float* out = (float*)d_out;

    const size_t wbytes   = (size_t)(K1 * N1 + N1 * N2) * sizeof(f16);   // 384 KB
    const size_t embbytes = (size_t)N_NODES * HDIM * sizeof(f16);        // 25.6 MB
    const size_t tabbytes = (size_t)N_NODES * 512 * sizeof(f16);         // 102.4 MB
    const size_t need_new = wbytes + embbytes + tabbytes;                // ~128.4 MB

    f16* W1F = (f16*)d_ws;
    f16* W2F = W1F + K1 * N1;

    const int prep_total = K1 * N1 + N1 * N2;
    prep_weights<<<(prep_total + 255) / 256, 256, 0, stream>>>(W1, W2, W1F, W2F);

    if (ws_size >= need_new) {
        // R18 path: emb16 + per-node A table; hybrid edge kernel
        f16* emb16 = W2F + N1 * N2;
        f16* Atab  = emb16 + (size_t)N_NODES * HDIM;
        const int cvt_threads = N_NODES * HDIM / 4;
        prep_emb<<<cvt_threads / 256, 256, 0, stream>>>(emb, emb16);
        precompute_A<<<(N_NODES + 63) / 64, BLOCK, 0, stream>>>(emb, W1F, b1, Atab);
        edge_mlp3<<<E_TOTAL / M_TILE, BLOCK, 0, stream>>>(
            emb16, Atab, eidx, W1F, W2F, b2, W3, b3, out);
    } else if (ws_size >= wbytes + embbytes) {
        f16* emb16 = W2F + N1 * N2;
        const int cvt_threads = N_NODES * HDIM / 4;
        prep_emb<<<cvt_threads / 256, 256, 0, stream>>>(emb, emb16);
        edge_mlp_kernel<true><<<E_TOTAL / M_TILE, BLOCK, 0, stream>>>(
            emb, emb16, eidx, W1F, b1, W2F, b2, W3, b3, out);
    } else {
        edge_mlp_kernel<false><<<E_TOTAL / M_TILE, BLOCK, 0, stream>>>(
            emb, (const f16*)nullptr, eidx, W1F, b1, W2F, b2, W3, b3, out);
    }
}